// Round 5
// baseline (258.025 us; speedup 1.0000x reference)
//
#include <hip/hip_runtime.h>

typedef __attribute__((ext_vector_type(8))) short short8;
typedef __attribute__((ext_vector_type(4))) short bf16x4;
typedef __attribute__((ext_vector_type(4))) float floatx4;

#define T_SEQ 2048
#define NH    16
#define HD    64

// 16x16x16 bf16 MFMA (4 bf16/lane A,B; 4 f32/lane C) — gfx90a-era builtin name,
// valid on gfx950 (v_mfma_f32_16x16x16_bf16 per cdna4_isa.md §10).
#define MFMA16(a, b, c) __builtin_amdgcn_mfma_f32_16x16x16bf16_1k(a, b, c, 0, 0, 0)

__device__ __forceinline__ ushort f2bf(float f) {
    union { float f; unsigned u; } un; un.f = f;
    unsigned r = un.u + 0x7fff + ((un.u >> 16) & 1);
    return (ushort)(r >> 16);
}

typedef const __attribute__((address_space(1))) unsigned int* gp1_t;
typedef __attribute__((address_space(3))) unsigned int* lp3_t;
__device__ __forceinline__ void gl_lds16(const ushort* g, ushort* l) {
    __builtin_amdgcn_global_load_lds((gp1_t)g, (lp3_t)l, 16, 0, 0);
}

// -------- transpose + convert: in fp32 [R][C] -> out bf16 [C][R] ----------
__global__ void transpose_f32_bf16(const float* __restrict__ in, ushort* __restrict__ out,
                                   int R, int C) {
    __shared__ ushort tile[32][33];
    const int tx = threadIdx.x & 31, ty = threadIdx.x >> 5;
    const int bx = blockIdx.x * 32;
    const int by = blockIdx.y * 32;
    #pragma unroll
    for (int i = ty; i < 32; i += 8)
        tile[i][tx] = f2bf(in[(size_t)(by + i) * C + bx + tx]);
    __syncthreads();
    #pragma unroll
    for (int i = ty; i < 32; i += 8)
        out[(size_t)(bx + i) * R + by + tx] = tile[tx][i];
}

// -------- elementwise fp32 -> bf16 ----------
__global__ void convert_f32_bf16(const float* __restrict__ in, ushort* __restrict__ out) {
    size_t i = ((size_t)blockIdx.x * 256 + threadIdx.x) * 8;
    float4 f0 = *(const float4*)(in + i);
    float4 f1 = *(const float4*)(in + i + 4);
    short8 v;
    v[0] = (short)f2bf(f0.x); v[1] = (short)f2bf(f0.y);
    v[2] = (short)f2bf(f0.z); v[3] = (short)f2bf(f0.w);
    v[4] = (short)f2bf(f1.x); v[5] = (short)f2bf(f1.y);
    v[6] = (short)f2bf(f1.z); v[7] = (short)f2bf(f1.w);
    *(short8*)(out + i) = v;
}

// ---------------- GEMM: C[M][N] = A[M][K] * Bt[N][K]^T  (bf16 MFMA, fp32 acc) --
template <int EPI>
__global__ __launch_bounds__(256, 2)
void gemm_bt(const ushort* __restrict__ A, const ushort* __restrict__ Bt,
             void* __restrict__ O0, ushort* __restrict__ O1, ushort* __restrict__ O2,
             int M, int N, int K) {
    __shared__ __align__(16) ushort As[128 * 32];
    __shared__ __align__(16) ushort Bs[128 * 32];
    const int tid  = threadIdx.x;
    const int wave = tid >> 6, lane = tid & 63;
    const int quad = lane >> 4, l16 = lane & 15;
    const int wm = (wave >> 1) * 64, wn = (wave & 1) * 64;
    const int m0 = blockIdx.x * 128, n0 = blockIdx.y * 128;

    const int c0 = tid, c1 = tid + 256;
    const int row0 = c0 >> 2, row1 = c1 >> 2;
    const int g0 = (((c0 & 3) ^ ((row0 >> 1) & 3))) * 8;
    const int g1 = (((c1 & 3) ^ ((row1 >> 1) & 3))) * 8;
    const ushort* aP0 = A  + (size_t)(m0 + row0) * K + g0;
    const ushort* aP1 = A  + (size_t)(m0 + row1) * K + g1;
    const ushort* bP0 = Bt + (size_t)(n0 + row0) * K + g0;
    const ushort* bP1 = Bt + (size_t)(n0 + row1) * K + g1;

    floatx4 acc[4][4];
    #pragma unroll
    for (int i = 0; i < 4; i++)
        #pragma unroll
        for (int j = 0; j < 4; j++)
            acc[i][j] = (floatx4){0.f, 0.f, 0.f, 0.f};

    const int col_sw = (quad ^ ((l16 >> 1) & 3)) * 8;

    for (int k0 = 0; k0 < K; k0 += 32) {
        __syncthreads();
        gl_lds16(aP0 + k0, &As[c0 * 8]);
        gl_lds16(aP1 + k0, &As[c1 * 8]);
        gl_lds16(bP0 + k0, &Bs[c0 * 8]);
        gl_lds16(bP1 + k0, &Bs[c1 * 8]);
        __syncthreads();
        short8 af[4], bf[4];
        #pragma unroll
        for (int i = 0; i < 4; i++)
            af[i] = *(const short8*)(&As[(wm + i * 16 + l16) * 32 + col_sw]);
        #pragma unroll
        for (int j = 0; j < 4; j++)
            bf[j] = *(const short8*)(&Bs[(wn + j * 16 + l16) * 32 + col_sw]);
        #pragma unroll
        for (int i = 0; i < 4; i++)
            #pragma unroll
            for (int j = 0; j < 4; j++)
                acc[i][j] = __builtin_amdgcn_mfma_f32_16x16x32_bf16(af[i], bf[j], acc[i][j], 0, 0, 0);
    }

    #pragma unroll
    for (int i = 0; i < 4; i++) {
        #pragma unroll
        for (int j = 0; j < 4; j++) {
            #pragma unroll
            for (int r = 0; r < 4; r++) {
                int m = m0 + wm + i * 16 + quad * 4 + r;
                int n = n0 + wn + j * 16 + l16;
                if (EPI == 0) {
                    ushort v = f2bf(acc[i][j][r]);
                    int b = m >> 11, t = m & 2047;
                    int part = n >> 10, c = n & 1023;
                    int head = c >> 6, off = c & 63;
                    if (part == 0)      ((ushort*)O0)[(((size_t)(b * NH + head)) * T_SEQ + t) * HD + off] = v;
                    else if (part == 1) O1[(((size_t)(b * NH + head)) * T_SEQ + t) * HD + off] = v;
                    else                O2[(((size_t)(b * NH + head)) * HD + off) * T_SEQ + t] = v;
                } else {
                    ((float*)O0)[(size_t)m * N + n] = acc[i][j][r];
                }
            }
        }
    }
}

// ---------------- flash attention, S^T formulation ---------------------------
// Block = (b,h, 128 q rows); wave owns 32 q rows (2 x 16 as MFMA N-dim).
// S^T = K·Q^T  (C: row=key=quad*4+r, col=q=l16)  -> per-lane scalar softmax state
// O^T = V^T·P^T via mfma_16x16x16 (P^T C-layout == B-operand layout: no LDS!)
// K/V staged by global_load_lds into double-buffered LDS, 1 barrier/tile.
__global__ __launch_bounds__(256, 4)
void attn_kernel(const ushort* __restrict__ Q, const ushort* __restrict__ Kk,
                 const ushort* __restrict__ Vt, ushort* __restrict__ Oout) {
    __shared__ __align__(16) ushort Ks[2][64 * 64];
    __shared__ __align__(16) ushort Vs[2][64 * 64];
    const int tid  = threadIdx.x;
    const int wave = tid >> 6, lane = tid & 63;
    const int quad = lane >> 4, l16 = lane & 15;
    const int idx = blockIdx.x;
    const int qb = 15 - (idx >> 5);    // heavy q-tiles dispatched first
    const int bh = idx & 31;
    const int b = bh >> 4, h = bh & 15;

    const ushort* qp = Q  + (size_t)bh * T_SEQ * HD;
    const ushort* kp = Kk + (size_t)bh * T_SEQ * HD;
    const ushort* vp = Vt + (size_t)bh * HD * T_SEQ;

    const int q0w = qb * 128 + wave * 32;

    // Q fragments (B-operand: n = q-row = l16, k = d = kb*32+quad*8..)
    short8 qf[2][2];
    #pragma unroll
    for (int qi = 0; qi < 2; qi++)
        #pragma unroll
        for (int kb = 0; kb < 2; kb++)
            qf[qi][kb] = *(const short8*)(qp + (size_t)(q0w + qi * 16 + l16) * HD + kb * 32 + quad * 8);

    floatx4 o[2][4];           // O^T accum: d = db*16+quad*4+r, q = l16 (per qi)
    float mst[2], lst[2];
    #pragma unroll
    for (int qi = 0; qi < 2; qi++) {
        #pragma unroll
        for (int db = 0; db < 4; db++) o[qi][db] = (floatx4){0.f, 0.f, 0.f, 0.f};
        mst[qi] = -1e30f; lst[qi] = 0.f;
    }

    // staging: 512 chunks of 16B per operand; thread covers c = tid, tid+256.
    // LDS chunk (row, p) holds global chunk p ^ (row&7)  (XOR on the GLOBAL side,
    // LDS side stays lane-contiguous for global_load_lds).
    const int c0 = tid, c1 = tid + 256;
    const int r0 = c0 >> 3, r1 = c1 >> 3;
    const int g0 = ((c0 & 7) ^ (r0 & 7)) * 8;
    const int g1 = ((c1 & 7) ^ (r1 & 7)) * 8;
    const size_t koff0 = (size_t)r0 * HD + g0,     koff1 = (size_t)r1 * HD + g1;
    const size_t voff0 = (size_t)r0 * T_SEQ + g0,  voff1 = (size_t)r1 * T_SEQ + g1;

    // prologue: issue tile 0 into buf 0
    gl_lds16(kp + koff0, &Ks[0][c0 * 8]);
    gl_lds16(kp + koff1, &Ks[0][c1 * 8]);
    gl_lds16(vp + voff0, &Vs[0][c0 * 8]);
    gl_lds16(vp + voff1, &Vs[0][c1 * 8]);

    const int n_kt = 2 * qb + 2;
    const float scale2 = 0.125f * 1.44269504088896f;   // exp2 domain
    const int xsw = (l16 & 7);

    for (int kt = 0; kt < n_kt; ++kt) {
        const int buf = kt & 1;
        __syncthreads();   // tile-kt staging complete (compiler drains vmcnt here)
        if (kt + 1 < n_kt) {      // issue kt+1 into other buffer; flies during compute
            const size_t kbase = (size_t)(kt + 1) * 64 * HD;
            const int    vbase = (kt + 1) * 64;
            gl_lds16(kp + kbase + koff0, &Ks[buf ^ 1][c0 * 8]);
            gl_lds16(kp + kbase + koff1, &Ks[buf ^ 1][c1 * 8]);
            gl_lds16(vp + vbase + voff0, &Vs[buf ^ 1][c0 * 8]);
            gl_lds16(vp + vbase + voff1, &Vs[buf ^ 1][c1 * 8]);
        }

        if (kt * 64 <= q0w + 31) {    // wave has unmasked work in this tile
            floatx4 s[2][4];
            #pragma unroll
            for (int qi = 0; qi < 2; qi++)
                #pragma unroll
                for (int j = 0; j < 4; j++) s[qi][j] = (floatx4){0.f, 0.f, 0.f, 0.f};

            // S^T: A = K-frag (m = key), B = Q-frag (n = q)
            #pragma unroll
            for (int kb = 0; kb < 2; kb++)
                #pragma unroll
                for (int j = 0; j < 4; j++) {
                    short8 kf = *(const short8*)(&Ks[buf][(j * 16 + l16) * 64 + (((kb * 4 + quad) ^ xsw) * 8)]);
                    #pragma unroll
                    for (int qi = 0; qi < 2; qi++)
                        s[qi][j] = __builtin_amdgcn_mfma_f32_16x16x32_bf16(kf, qf[qi][kb], s[qi][j], 0, 0, 0);
                }

            if (kt * 64 + 63 > q0w) {   // tile touches diagonal for this wave
                #pragma unroll
                for (int qi = 0; qi < 2; qi++)
                    #pragma unroll
                    for (int j = 0; j < 4; j++)
                        #pragma unroll
                        for (int r = 0; r < 4; r++) {
                            int key = kt * 64 + j * 16 + quad * 4 + r;
                            int row = q0w + qi * 16 + l16;
                            float v = s[qi][j][r] * scale2;
                            s[qi][j][r] = (key > row) ? -1e30f : v;
                        }
            } else {
                #pragma unroll
                for (int qi = 0; qi < 2; qi++)
                    #pragma unroll
                    for (int j = 0; j < 4; j++)
                        #pragma unroll
                        for (int r = 0; r < 4; r++) s[qi][j][r] *= scale2;
            }

            bf16x4 pf[2][4];
            #pragma unroll
            for (int qi = 0; qi < 2; qi++) {
                float t = s[qi][0][0];
                #pragma unroll
                for (int j = 0; j < 4; j++)
                    #pragma unroll
                    for (int r = 0; r < 4; r++) t = fmaxf(t, s[qi][j][r]);
                t = fmaxf(t, __shfl_xor(t, 16));
                t = fmaxf(t, __shfl_xor(t, 32));
                float mnew  = fmaxf(mst[qi], t);
                float alpha = exp2f(mst[qi] - mnew);
                mst[qi] = mnew;
                float lsum = 0.f;
                #pragma unroll
                for (int j = 0; j < 4; j++) {
                    bf16x4 p4;
                    #pragma unroll
                    for (int r = 0; r < 4; r++) {
                        float p = exp2f(s[qi][j][r] - mnew);
                        lsum += p;
                        p4[r] = (short)f2bf(p);
                    }
                    pf[qi][j] = p4;
                }
                lsum += __shfl_xor(lsum, 16);
                lsum += __shfl_xor(lsum, 32);
                lst[qi] = lst[qi] * alpha + lsum;
                #pragma unroll
                for (int db = 0; db < 4; db++)
                    #pragma unroll
                    for (int r = 0; r < 4; r++) o[qi][db][r] *= alpha;
            }

            // O^T += V^T · P^T  via 16x16x16 (A = V^T frag, B = P^T = QK C-tile)
            #pragma unroll
            for (int j = 0; j < 4; j++) {
                const int gchunk = 2 * j + (quad >> 1);
                #pragma unroll
                for (int db = 0; db < 4; db++) {
                    bf16x4 vf = *(const bf16x4*)(&Vs[buf][(db * 16 + l16) * 64 +
                                                          ((gchunk ^ xsw) * 8) + (quad & 1) * 4]);
                    #pragma unroll
                    for (int qi = 0; qi < 2; qi++)
                        o[qi][db] = MFMA16(vf, pf[qi][j], o[qi][db]);
                }
            }
        }
    }

    #pragma unroll
    for (int qi = 0; qi < 2; qi++) {
        const float inv = 1.0f / lst[qi];
        const int t = q0w + qi * 16 + l16;
        #pragma unroll
        for (int db = 0; db < 4; db++) {
            ushort4 w;
            w.x = f2bf(o[qi][db][0] * inv);
            w.y = f2bf(o[qi][db][1] * inv);
            w.z = f2bf(o[qi][db][2] * inv);
            w.w = f2bf(o[qi][db][3] * inv);
            *(ushort4*)(Oout + (((size_t)b * T_SEQ + t) * NH + h) * HD + db * 16 + quad * 4) = w;
        }
    }
}

extern "C" void kernel_launch(void* const* d_in, const int* in_sizes, int n_in,
                              void* d_out, int out_size, void* d_ws, size_t ws_size,
                              hipStream_t stream) {
    const float* x    = (const float*)d_in[0];   // [2,2048,1024] fp32
    const float* Wqkv = (const float*)d_in[1];   // [1024,3072]  fp32
    const float* Wout = (const float*)d_in[2];   // [1024,1024]  fp32
    ushort* ws = (ushort*)d_ws;

    ushort* wt_qkv = ws;                               // bf16 [3072][1024]
    ushort* wt_out = wt_qkv + 3072 * 1024;             // bf16 [1024][1024]
    ushort* q_ws   = wt_out + 1024 * 1024;             // bf16 [B,H,T,hd]
    ushort* k_ws   = q_ws + 4194304;
    ushort* v_t    = k_ws + 4194304;                   // bf16 [B,H,hd,T]
    ushort* a_out  = v_t + 4194304;                    // bf16 [B,T,C]
    ushort* x_bf   = a_out + 4194304;                  // bf16 [B,T,C]

    transpose_f32_bf16<<<dim3(96, 32), 256, 0, stream>>>(Wqkv, wt_qkv, 1024, 3072);
    transpose_f32_bf16<<<dim3(32, 32), 256, 0, stream>>>(Wout, wt_out, 1024, 1024);
    convert_f32_bf16<<<dim3(2048), 256, 0, stream>>>(x, x_bf);

    gemm_bt<0><<<dim3(32, 24), 256, 0, stream>>>(x_bf, wt_qkv, q_ws, k_ws, v_t, 4096, 3072, 1024);

    attn_kernel<<<dim3(512), 256, 0, stream>>>(q_ws, k_ws, v_t, a_out);

    gemm_bt<1><<<dim3(32, 8), 256, 0, stream>>>(a_out, wt_out, (float*)d_out, nullptr, nullptr,
                                                4096, 1024, 1024);
}

// Round 6
// 225.612 us; speedup vs baseline: 1.1437x; 1.1437x over previous
//
#include <hip/hip_runtime.h>
#include <hip/hip_bf16.h>

typedef __attribute__((ext_vector_type(8))) short short8;
typedef __attribute__((ext_vector_type(4))) short bf16x4;
typedef __attribute__((ext_vector_type(4))) float floatx4;

#define T_SEQ 2048
#define NH    16
#define HD    64
#define QSCALE 0.18033688f   // 0.125 * log2(e): folded into Q at GEMM1 epilogue

// v_mfma_f32_16x16x16_bf16 (4 bf16/lane A,B; 4 f32/lane C)
#define MFMA16(a, b, c) __builtin_amdgcn_mfma_f32_16x16x16bf16_1k(a, b, c, 0, 0, 0)

__device__ __forceinline__ ushort f2bf(float f) {
    union { float f; unsigned u; } un; un.f = f;
    unsigned r = un.u + 0x7fff + ((un.u >> 16) & 1);
    return (ushort)(r >> 16);
}
__device__ __forceinline__ unsigned pkbf(float a, float b) {   // packed cvt (1 inst)
    __hip_bfloat162 t = __float22bfloat162_rn(float2{a, b});
    return *reinterpret_cast<unsigned*>(&t);
}

typedef const __attribute__((address_space(1))) unsigned int* gp1_t;
typedef __attribute__((address_space(3))) unsigned int* lp3_t;
__device__ __forceinline__ void gl_lds16(const ushort* g, ushort* l) {
    __builtin_amdgcn_global_load_lds((gp1_t)g, (lp3_t)l, 16, 0, 0);
}

// -------- transpose + convert: in fp32 [R][C] -> out bf16 [C][R] ----------
__global__ void transpose_f32_bf16(const float* __restrict__ in, ushort* __restrict__ out,
                                   int R, int C) {
    __shared__ ushort tile[32][33];
    const int tx = threadIdx.x & 31, ty = threadIdx.x >> 5;
    const int bx = blockIdx.x * 32;
    const int by = blockIdx.y * 32;
    #pragma unroll
    for (int i = ty; i < 32; i += 8)
        tile[i][tx] = f2bf(in[(size_t)(by + i) * C + bx + tx]);
    __syncthreads();
    #pragma unroll
    for (int i = ty; i < 32; i += 8)
        out[(size_t)(bx + i) * R + by + tx] = tile[tx][i];
}

// -------- elementwise fp32 -> bf16 ----------
__global__ void convert_f32_bf16(const float* __restrict__ in, ushort* __restrict__ out) {
    size_t i = ((size_t)blockIdx.x * 256 + threadIdx.x) * 8;
    float4 f0 = *(const float4*)(in + i);
    float4 f1 = *(const float4*)(in + i + 4);
    short8 v;
    v[0] = (short)f2bf(f0.x); v[1] = (short)f2bf(f0.y);
    v[2] = (short)f2bf(f0.z); v[3] = (short)f2bf(f0.w);
    v[4] = (short)f2bf(f1.x); v[5] = (short)f2bf(f1.y);
    v[6] = (short)f2bf(f1.z); v[7] = (short)f2bf(f1.w);
    *(short8*)(out + i) = v;
}

// ---------------- GEMM: C[M][N] = A[M][K] * Bt[N][K]^T  (bf16 MFMA, fp32 acc) --
// EPI==0: scatter bf16 into q(pre-scaled)[B,H,T,hd], k[B,H,T,hd], vT[B,H,hd,T]
// EPI==1: fp32 row-major [M][N]
template <int EPI>
__global__ __launch_bounds__(256, 2)
void gemm_bt(const ushort* __restrict__ A, const ushort* __restrict__ Bt,
             void* __restrict__ O0, ushort* __restrict__ O1, ushort* __restrict__ O2,
             int M, int N, int K) {
    __shared__ __align__(16) ushort As[128 * 32];
    __shared__ __align__(16) ushort Bs[128 * 32];
    const int tid  = threadIdx.x;
    const int wave = tid >> 6, lane = tid & 63;
    const int quad = lane >> 4, l16 = lane & 15;
    const int wm = (wave >> 1) * 64, wn = (wave & 1) * 64;
    const int m0 = blockIdx.x * 128, n0 = blockIdx.y * 128;

    const int c0 = tid, c1 = tid + 256;
    const int row0 = c0 >> 2, row1 = c1 >> 2;
    const int g0 = (((c0 & 3) ^ ((row0 >> 1) & 3))) * 8;
    const int g1 = (((c1 & 3) ^ ((row1 >> 1) & 3))) * 8;
    const ushort* aP0 = A  + (size_t)(m0 + row0) * K + g0;
    const ushort* aP1 = A  + (size_t)(m0 + row1) * K + g1;
    const ushort* bP0 = Bt + (size_t)(n0 + row0) * K + g0;
    const ushort* bP1 = Bt + (size_t)(n0 + row1) * K + g1;

    floatx4 acc[4][4];
    #pragma unroll
    for (int i = 0; i < 4; i++)
        #pragma unroll
        for (int j = 0; j < 4; j++)
            acc[i][j] = (floatx4){0.f, 0.f, 0.f, 0.f};

    const int col_sw = (quad ^ ((l16 >> 1) & 3)) * 8;

    for (int k0 = 0; k0 < K; k0 += 32) {
        __syncthreads();
        gl_lds16(aP0 + k0, &As[c0 * 8]);
        gl_lds16(aP1 + k0, &As[c1 * 8]);
        gl_lds16(bP0 + k0, &Bs[c0 * 8]);
        gl_lds16(bP1 + k0, &Bs[c1 * 8]);
        __syncthreads();
        short8 af[4], bf[4];
        #pragma unroll
        for (int i = 0; i < 4; i++)
            af[i] = *(const short8*)(&As[(wm + i * 16 + l16) * 32 + col_sw]);
        #pragma unroll
        for (int j = 0; j < 4; j++)
            bf[j] = *(const short8*)(&Bs[(wn + j * 16 + l16) * 32 + col_sw]);
        #pragma unroll
        for (int i = 0; i < 4; i++)
            #pragma unroll
            for (int j = 0; j < 4; j++)
                acc[i][j] = __builtin_amdgcn_mfma_f32_16x16x32_bf16(af[i], bf[j], acc[i][j], 0, 0, 0);
    }

    #pragma unroll
    for (int i = 0; i < 4; i++) {
        #pragma unroll
        for (int j = 0; j < 4; j++) {
            #pragma unroll
            for (int r = 0; r < 4; r++) {
                int m = m0 + wm + i * 16 + quad * 4 + r;
                int n = n0 + wn + j * 16 + l16;
                if (EPI == 0) {
                    int b = m >> 11, t = m & 2047;
                    int part = n >> 10, c = n & 1023;
                    int head = c >> 6, off = c & 63;
                    float av = acc[i][j][r];
                    if (part == 0) av *= QSCALE;     // pre-scale Q for attention
                    ushort v = f2bf(av);
                    if (part == 0)      ((ushort*)O0)[(((size_t)(b * NH + head)) * T_SEQ + t) * HD + off] = v;
                    else if (part == 1) O1[(((size_t)(b * NH + head)) * T_SEQ + t) * HD + off] = v;
                    else                O2[(((size_t)(b * NH + head)) * HD + off) * T_SEQ + t] = v;
                } else {
                    ((float*)O0)[(size_t)m * N + n] = acc[i][j][r];
                }
            }
        }
    }
}

// ---------------- flash attention, S^T formulation, 64-row q blocks ----------
// Block = (bh, 64 q rows); 4 waves, wave owns 16 q rows (MFMA N-dim).
// S^T = K·Q^T  (C: row=key=quad*4+r, col=q=l16) -> per-lane scalar softmax state
// O^T = V^T·P^T via mfma_16x16x16 (P^T C-layout == B-operand layout: in regs)
// K/V staged by global_load_lds into double-buffered LDS, 1 barrier/tile.
// Grid 1024 blocks -> 4 blocks/CU (LDS 32KB), bh-major for L2, heavy qt first.
__global__ __launch_bounds__(256, 4)
void attn_kernel(const ushort* __restrict__ Q, const ushort* __restrict__ Kk,
                 const ushort* __restrict__ Vt, ushort* __restrict__ Oout) {
    __shared__ __align__(16) ushort Ks[2][64 * 64];
    __shared__ __align__(16) ushort Vs[2][64 * 64];
    const int tid  = threadIdx.x;
    const int wave = tid >> 6, lane = tid & 63;
    const int quad = lane >> 4, l16 = lane & 15;
    const int idx = blockIdx.x;
    const int bh = idx >> 5;            // 32 consecutive blocks share one bh's K/V
    const int qt = 31 - (idx & 31);     // heavy q-tiles first
    const int b = bh >> 4, h = bh & 15;

    const ushort* qp = Q  + (size_t)bh * T_SEQ * HD;
    const ushort* kp = Kk + (size_t)bh * T_SEQ * HD;
    const ushort* vp = Vt + (size_t)bh * HD * T_SEQ;

    const int q0w = qt * 64 + wave * 16;   // this wave's 16 q rows

    // Q fragments (B-operand: n = q-row = l16, k = d = kb*32+quad*8..); pre-scaled
    short8 qf[2];
    #pragma unroll
    for (int kb = 0; kb < 2; kb++)
        qf[kb] = *(const short8*)(qp + (size_t)(q0w + l16) * HD + kb * 32 + quad * 8);

    floatx4 o[4];              // O^T accum: d = db*16+quad*4+r, q = l16
    #pragma unroll
    for (int db = 0; db < 4; db++) o[db] = (floatx4){0.f, 0.f, 0.f, 0.f};
    float mst = -1e30f, lst = 0.f;

    // staging: 512 chunks of 16B per operand; thread covers c = tid, tid+256.
    // LDS chunk (row r, p) holds global chunk p ^ (r&7) (XOR on the GLOBAL side).
    const int c0 = tid, c1 = tid + 256;
    const int r0 = c0 >> 3, r1 = c1 >> 3;
    const int g0 = ((c0 & 7) ^ (r0 & 7)) * 8;
    const int g1 = ((c1 & 7) ^ (r1 & 7)) * 8;
    const size_t koff0 = (size_t)r0 * HD + g0,     koff1 = (size_t)r1 * HD + g1;
    const size_t voff0 = (size_t)r0 * T_SEQ + g0,  voff1 = (size_t)r1 * T_SEQ + g1;

    gl_lds16(kp + koff0, &Ks[0][c0 * 8]);
    gl_lds16(kp + koff1, &Ks[0][c1 * 8]);
    gl_lds16(vp + voff0, &Vs[0][c0 * 8]);
    gl_lds16(vp + voff1, &Vs[0][c1 * 8]);

    const int n_kt = qt + 1;
    const int xsw = (l16 & 7);

    for (int kt = 0; kt < n_kt; ++kt) {
        const int buf = kt & 1;
        __syncthreads();               // tile-kt staging complete
        if (kt + 1 < n_kt) {           // issue kt+1; lands during compute
            const size_t kbase = (size_t)(kt + 1) * 64 * HD;
            const int    vbase = (kt + 1) * 64;
            gl_lds16(kp + kbase + koff0, &Ks[buf ^ 1][c0 * 8]);
            gl_lds16(kp + kbase + koff1, &Ks[buf ^ 1][c1 * 8]);
            gl_lds16(vp + vbase + voff0, &Vs[buf ^ 1][c0 * 8]);
            gl_lds16(vp + vbase + voff1, &Vs[buf ^ 1][c1 * 8]);
        }

        // S^T: A = K-frag (m = key), B = Q-frag (n = q)
        floatx4 s[4];
        #pragma unroll
        for (int j = 0; j < 4; j++) s[j] = (floatx4){0.f, 0.f, 0.f, 0.f};
        #pragma unroll
        for (int kb = 0; kb < 2; kb++)
            #pragma unroll
            for (int j = 0; j < 4; j++) {
                short8 kf = *(const short8*)(&Ks[buf][(j * 16 + l16) * 64 + (((kb * 4 + quad) ^ xsw) * 8)]);
                s[j] = __builtin_amdgcn_mfma_f32_16x16x32_bf16(kf, qf[kb], s[j], 0, 0, 0);
            }

        if (kt == qt) {   // diagonal tile: causal mask (scale already folded into Q)
            #pragma unroll
            for (int j = 0; j < 4; j++)
                #pragma unroll
                for (int r = 0; r < 4; r++) {
                    int key = kt * 64 + j * 16 + quad * 4 + r;
                    int row = q0w + l16;
                    if (key > row) s[j][r] = -1e30f;
                }
        }

        // per-lane softmax over 16 values + quad reduction (2 shuffles)
        float t0 = fmaxf(fmaxf(s[0][0], s[0][1]), fmaxf(s[0][2], s[0][3]));
        float t1 = fmaxf(fmaxf(s[1][0], s[1][1]), fmaxf(s[1][2], s[1][3]));
        float t2 = fmaxf(fmaxf(s[2][0], s[2][1]), fmaxf(s[2][2], s[2][3]));
        float t3 = fmaxf(fmaxf(s[3][0], s[3][1]), fmaxf(s[3][2], s[3][3]));
        float t = fmaxf(fmaxf(t0, t1), fmaxf(t2, t3));
        t = fmaxf(t, __shfl_xor(t, 16));
        t = fmaxf(t, __shfl_xor(t, 32));
        float mnew  = fmaxf(mst, t);
        float alpha = exp2f(mst - mnew);
        mst = mnew;

        bf16x4 pf[4];
        float lsum = 0.f;
        #pragma unroll
        for (int j = 0; j < 4; j++) {
            float p0 = exp2f(s[j][0] - mnew);
            float p1 = exp2f(s[j][1] - mnew);
            float p2 = exp2f(s[j][2] - mnew);
            float p3 = exp2f(s[j][3] - mnew);
            lsum += (p0 + p1) + (p2 + p3);
            union { bf16x4 v; unsigned u[2]; } pu;
            pu.u[0] = pkbf(p0, p1);
            pu.u[1] = pkbf(p2, p3);
            pf[j] = pu.v;
        }
        lsum += __shfl_xor(lsum, 16);
        lsum += __shfl_xor(lsum, 32);
        lst = lst * alpha + lsum;
        #pragma unroll
        for (int db = 0; db < 4; db++)
            #pragma unroll
            for (int r = 0; r < 4; r++) o[db][r] *= alpha;

        // O^T += V^T · P^T  (A = V^T frag, B = P^T = S^T C-tile, already in regs)
        #pragma unroll
        for (int j = 0; j < 4; j++) {
            const int gchunk = 2 * j + (quad >> 1);
            #pragma unroll
            for (int db = 0; db < 4; db++) {
                bf16x4 vf = *(const bf16x4*)(&Vs[buf][(db * 16 + l16) * 64 +
                                                      ((gchunk ^ xsw) * 8) + (quad & 1) * 4]);
                o[db] = MFMA16(vf, pf[j], o[db]);
            }
        }
    }

    const float inv = 1.0f / lst;
    const int t = q0w + l16;
    #pragma unroll
    for (int db = 0; db < 4; db++) {
        union { ushort4 w; unsigned u[2]; } ou;
        ou.u[0] = pkbf(o[db][0] * inv, o[db][1] * inv);
        ou.u[1] = pkbf(o[db][2] * inv, o[db][3] * inv);
        *(ushort4*)(Oout + (((size_t)b * T_SEQ + t) * NH + h) * HD + db * 16 + quad * 4) = ou.w;
    }
}

extern "C" void kernel_launch(void* const* d_in, const int* in_sizes, int n_in,
                              void* d_out, int out_size, void* d_ws, size_t ws_size,
                              hipStream_t stream) {
    const float* x    = (const float*)d_in[0];   // [2,2048,1024] fp32
    const float* Wqkv = (const float*)d_in[1];   // [1024,3072]  fp32
    const float* Wout = (const float*)d_in[2];   // [1024,1024]  fp32
    ushort* ws = (ushort*)d_ws;

    ushort* wt_qkv = ws;                               // bf16 [3072][1024]
    ushort* wt_out = wt_qkv + 3072 * 1024;             // bf16 [1024][1024]
    ushort* q_ws   = wt_out + 1024 * 1024;             // bf16 [B,H,T,hd] (pre-scaled)
    ushort* k_ws   = q_ws + 4194304;
    ushort* v_t    = k_ws + 4194304;                   // bf16 [B,H,hd,T]
    ushort* a_out  = v_t + 4194304;                    // bf16 [B,T,C]
    ushort* x_bf   = a_out + 4194304;                  // bf16 [B,T,C]

    transpose_f32_bf16<<<dim3(96, 32), 256, 0, stream>>>(Wqkv, wt_qkv, 1024, 3072);
    transpose_f32_bf16<<<dim3(32, 32), 256, 0, stream>>>(Wout, wt_out, 1024, 1024);
    convert_f32_bf16<<<dim3(2048), 256, 0, stream>>>(x, x_bf);

    gemm_bt<0><<<dim3(32, 24), 256, 0, stream>>>(x_bf, wt_qkv, q_ws, k_ws, v_t, 4096, 3072, 1024);

    attn_kernel<<<dim3(1024), 256, 0, stream>>>(q_ws, k_ws, v_t, a_out);

    gemm_bt<1><<<dim3(32, 8), 256, 0, stream>>>(a_out, wt_out, (float*)d_out, nullptr, nullptr,
                                                4096, 1024, 1024);
}

// Round 7
// 221.499 us; speedup vs baseline: 1.1649x; 1.0186x over previous
//
#include <hip/hip_runtime.h>
#include <hip/hip_bf16.h>

typedef __attribute__((ext_vector_type(8))) short short8;
typedef __attribute__((ext_vector_type(4))) short bf16x4;
typedef __attribute__((ext_vector_type(4))) float floatx4;

#define T_SEQ 2048
#define NH    16
#define HD    64
#define QSCALE 0.18033688f   // 0.125 * log2(e): folded into Q at GEMM1 epilogue

// v_mfma_f32_16x16x16_bf16 (4 bf16/lane A,B; 4 f32/lane C)
#define MFMA16(a, b, c) __builtin_amdgcn_mfma_f32_16x16x16bf16_1k(a, b, c, 0, 0, 0)

__device__ __forceinline__ ushort f2bf(float f) {
    union { float f; unsigned u; } un; un.f = f;
    unsigned r = un.u + 0x7fff + ((un.u >> 16) & 1);
    return (ushort)(r >> 16);
}
__device__ __forceinline__ unsigned pkbf(float a, float b) {   // packed cvt (1 inst)
    __hip_bfloat162 t = __float22bfloat162_rn(float2{a, b});
    return *reinterpret_cast<unsigned*>(&t);
}

typedef const __attribute__((address_space(1))) unsigned int* gp1_t;
typedef __attribute__((address_space(3))) unsigned int* lp3_t;
__device__ __forceinline__ void gl_lds16(const ushort* g, ushort* l) {
    __builtin_amdgcn_global_load_lds((gp1_t)g, (lp3_t)l, 16, 0, 0);
}

// -------- transpose + convert: in fp32 [R][C] -> out bf16 [C][R] ----------
__global__ void transpose_f32_bf16(const float* __restrict__ in, ushort* __restrict__ out,
                                   int R, int C) {
    __shared__ ushort tile[32][33];
    const int tx = threadIdx.x & 31, ty = threadIdx.x >> 5;
    const int bx = blockIdx.x * 32;
    const int by = blockIdx.y * 32;
    #pragma unroll
    for (int i = ty; i < 32; i += 8)
        tile[i][tx] = f2bf(in[(size_t)(by + i) * C + bx + tx]);
    __syncthreads();
    #pragma unroll
    for (int i = ty; i < 32; i += 8)
        out[(size_t)(bx + i) * R + by + tx] = tile[tx][i];
}

// -------- elementwise fp32 -> bf16 ----------
__global__ void convert_f32_bf16(const float* __restrict__ in, ushort* __restrict__ out) {
    size_t i = ((size_t)blockIdx.x * 256 + threadIdx.x) * 8;
    float4 f0 = *(const float4*)(in + i);
    float4 f1 = *(const float4*)(in + i + 4);
    short8 v;
    v[0] = (short)f2bf(f0.x); v[1] = (short)f2bf(f0.y);
    v[2] = (short)f2bf(f0.z); v[3] = (short)f2bf(f0.w);
    v[4] = (short)f2bf(f1.x); v[5] = (short)f2bf(f1.y);
    v[6] = (short)f2bf(f1.z); v[7] = (short)f2bf(f1.w);
    *(short8*)(out + i) = v;
}

// ---------------- GEMM: C[M][N] = A[M][K] * Bt[N][K]^T  (bf16 MFMA, fp32 acc) --
// EPI==0: scatter bf16 into q(pre-scaled)[B,H,T,hd], k[B,H,T,hd], vT[B,H,hd,T]
// EPI==1: fp32 row-major [M][N]
template <int EPI>
__global__ __launch_bounds__(256, 2)
void gemm_bt(const ushort* __restrict__ A, const ushort* __restrict__ Bt,
             void* __restrict__ O0, ushort* __restrict__ O1, ushort* __restrict__ O2,
             int M, int N, int K) {
    __shared__ __align__(16) ushort As[128 * 32];
    __shared__ __align__(16) ushort Bs[128 * 32];
    const int tid  = threadIdx.x;
    const int wave = tid >> 6, lane = tid & 63;
    const int quad = lane >> 4, l16 = lane & 15;
    const int wm = (wave >> 1) * 64, wn = (wave & 1) * 64;
    const int m0 = blockIdx.x * 128, n0 = blockIdx.y * 128;

    const int c0 = tid, c1 = tid + 256;
    const int row0 = c0 >> 2, row1 = c1 >> 2;
    const int g0 = (((c0 & 3) ^ ((row0 >> 1) & 3))) * 8;
    const int g1 = (((c1 & 3) ^ ((row1 >> 1) & 3))) * 8;
    const ushort* aP0 = A  + (size_t)(m0 + row0) * K + g0;
    const ushort* aP1 = A  + (size_t)(m0 + row1) * K + g1;
    const ushort* bP0 = Bt + (size_t)(n0 + row0) * K + g0;
    const ushort* bP1 = Bt + (size_t)(n0 + row1) * K + g1;

    floatx4 acc[4][4];
    #pragma unroll
    for (int i = 0; i < 4; i++)
        #pragma unroll
        for (int j = 0; j < 4; j++)
            acc[i][j] = (floatx4){0.f, 0.f, 0.f, 0.f};

    const int col_sw = (quad ^ ((l16 >> 1) & 3)) * 8;

    for (int k0 = 0; k0 < K; k0 += 32) {
        __syncthreads();
        gl_lds16(aP0 + k0, &As[c0 * 8]);
        gl_lds16(aP1 + k0, &As[c1 * 8]);
        gl_lds16(bP0 + k0, &Bs[c0 * 8]);
        gl_lds16(bP1 + k0, &Bs[c1 * 8]);
        __syncthreads();
        short8 af[4], bf[4];
        #pragma unroll
        for (int i = 0; i < 4; i++)
            af[i] = *(const short8*)(&As[(wm + i * 16 + l16) * 32 + col_sw]);
        #pragma unroll
        for (int j = 0; j < 4; j++)
            bf[j] = *(const short8*)(&Bs[(wn + j * 16 + l16) * 32 + col_sw]);
        #pragma unroll
        for (int i = 0; i < 4; i++)
            #pragma unroll
            for (int j = 0; j < 4; j++)
                acc[i][j] = __builtin_amdgcn_mfma_f32_16x16x32_bf16(af[i], bf[j], acc[i][j], 0, 0, 0);
    }

    #pragma unroll
    for (int i = 0; i < 4; i++) {
        #pragma unroll
        for (int j = 0; j < 4; j++) {
            #pragma unroll
            for (int r = 0; r < 4; r++) {
                int m = m0 + wm + i * 16 + quad * 4 + r;
                int n = n0 + wn + j * 16 + l16;
                if (EPI == 0) {
                    int b = m >> 11, t = m & 2047;
                    int part = n >> 10, c = n & 1023;
                    int head = c >> 6, off = c & 63;
                    float av = acc[i][j][r];
                    if (part == 0) av *= QSCALE;     // pre-scale Q for attention
                    ushort v = f2bf(av);
                    if (part == 0)      ((ushort*)O0)[(((size_t)(b * NH + head)) * T_SEQ + t) * HD + off] = v;
                    else if (part == 1) O1[(((size_t)(b * NH + head)) * T_SEQ + t) * HD + off] = v;
                    else                O2[(((size_t)(b * NH + head)) * HD + off) * T_SEQ + t] = v;
                } else {
                    ((float*)O0)[(size_t)m * N + n] = acc[i][j][r];
                }
            }
        }
    }
}

// -------- online-softmax step over one 64-key S^T tile (per-lane scalar state) --
__device__ __forceinline__ void softmax_step(floatx4 s[4], float& mst, float& lst,
                                             floatx4 o[4], bf16x4 pf[4]) {
    float t0 = fmaxf(fmaxf(s[0][0], s[0][1]), fmaxf(s[0][2], s[0][3]));
    float t1 = fmaxf(fmaxf(s[1][0], s[1][1]), fmaxf(s[1][2], s[1][3]));
    float t2 = fmaxf(fmaxf(s[2][0], s[2][1]), fmaxf(s[2][2], s[2][3]));
    float t3 = fmaxf(fmaxf(s[3][0], s[3][1]), fmaxf(s[3][2], s[3][3]));
    float t = fmaxf(fmaxf(t0, t1), fmaxf(t2, t3));
    t = fmaxf(t, __shfl_xor(t, 16));
    t = fmaxf(t, __shfl_xor(t, 32));
    float mnew  = fmaxf(mst, t);
    float alpha = exp2f(mst - mnew);
    mst = mnew;
    float lsum = 0.f;
    #pragma unroll
    for (int j = 0; j < 4; j++) {
        float p0 = exp2f(s[j][0] - mnew);
        float p1 = exp2f(s[j][1] - mnew);
        float p2 = exp2f(s[j][2] - mnew);
        float p3 = exp2f(s[j][3] - mnew);
        lsum += (p0 + p1) + (p2 + p3);
        union { bf16x4 v; unsigned u[2]; } pu;
        pu.u[0] = pkbf(p0, p1);
        pu.u[1] = pkbf(p2, p3);
        pf[j] = pu.v;
    }
    lsum += __shfl_xor(lsum, 16);
    lsum += __shfl_xor(lsum, 32);
    lst = lst * alpha + lsum;
    #pragma unroll
    for (int db = 0; db < 4; db++)
        #pragma unroll
        for (int r = 0; r < 4; r++) o[db][r] *= alpha;
}

// ---------------- flash attention, S^T formulation, paired q-tiles -----------
// Block = (bh, pair pr): q-tiles qtA=pr and qtB=31-pr -> exactly 33 MFMA
// tile-units per block (uniform). One K-loop kt=0..31-pr; while kt<=pr both
// tiles are active and each K/V LDS fragment read feeds BOTH q-tiles' MFMAs.
// pr = j<8 ? 2j : 31-2j (j=idx>>5) so co-scheduled blocks c,c+256 have
// complementary iteration counts (sum = 49).
// S^T = K·Q^T  (C: row=key, col=q) -> per-lane scalar softmax state.
// O^T = V^T·P^T via mfma_16x16x16 (P^T stays in registers as B-operand).
__global__ __launch_bounds__(256, 2)
void attn_kernel(const ushort* __restrict__ Q, const ushort* __restrict__ Kk,
                 const ushort* __restrict__ Vt, ushort* __restrict__ Oout) {
    __shared__ __align__(16) ushort Ks[2][64 * 64];
    __shared__ __align__(16) ushort Vs[2][64 * 64];
    const int tid  = threadIdx.x;
    const int wave = tid >> 6, lane = tid & 63;
    const int quad = lane >> 4, l16 = lane & 15;
    const int idx = blockIdx.x;
    const int bh = idx & 31;
    const int j16 = idx >> 5;                        // 0..15
    const int pr  = (j16 < 8) ? (2 * j16) : (31 - 2 * j16);   // 0..15, each once
    const int qtA = pr, qtB = 31 - pr;               // paired q-tiles
    const int KT  = qtB;                             // last K-tile index
    const int b = bh >> 4, h = bh & 15;

    const ushort* qp = Q  + (size_t)bh * T_SEQ * HD;
    const ushort* kp = Kk + (size_t)bh * T_SEQ * HD;
    const ushort* vp = Vt + (size_t)bh * HD * T_SEQ;

    const int qA0 = qtA * 64 + wave * 16;            // wave's 16 rows of tile A
    const int qB0 = qtB * 64 + wave * 16;            // wave's 16 rows of tile B

    // Q fragments (B-operand: n = q-row = l16, k = d = kb*32+quad*8..); pre-scaled
    short8 qfA[2], qfB[2];
    #pragma unroll
    for (int kb = 0; kb < 2; kb++) {
        qfA[kb] = *(const short8*)(qp + (size_t)(qA0 + l16) * HD + kb * 32 + quad * 8);
        qfB[kb] = *(const short8*)(qp + (size_t)(qB0 + l16) * HD + kb * 32 + quad * 8);
    }

    floatx4 oA[4], oB[4];      // O^T accum: d = db*16+quad*4+r, q = l16
    #pragma unroll
    for (int db = 0; db < 4; db++) {
        oA[db] = (floatx4){0.f, 0.f, 0.f, 0.f};
        oB[db] = (floatx4){0.f, 0.f, 0.f, 0.f};
    }
    float mA = -1e30f, lA = 0.f, mB = -1e30f, lB = 0.f;

    // staging: 512 chunks of 16B per operand; thread covers c = tid, tid+256.
    // LDS chunk (row r, p) holds global chunk p ^ (r&7) (XOR on the GLOBAL side).
    const int c0 = tid, c1 = tid + 256;
    const int r0 = c0 >> 3, r1 = c1 >> 3;
    const int g0 = ((c0 & 7) ^ (r0 & 7)) * 8;
    const int g1 = ((c1 & 7) ^ (r1 & 7)) * 8;
    const size_t koff0 = (size_t)r0 * HD + g0,     koff1 = (size_t)r1 * HD + g1;
    const size_t voff0 = (size_t)r0 * T_SEQ + g0,  voff1 = (size_t)r1 * T_SEQ + g1;

    gl_lds16(kp + koff0, &Ks[0][c0 * 8]);
    gl_lds16(kp + koff1, &Ks[0][c1 * 8]);
    gl_lds16(vp + voff0, &Vs[0][c0 * 8]);
    gl_lds16(vp + voff1, &Vs[0][c1 * 8]);

    const int xsw = (l16 & 7);

    for (int kt = 0; kt <= KT; ++kt) {
        const int buf = kt & 1;
        __syncthreads();               // tile-kt staging complete
        if (kt < KT) {                 // issue kt+1; lands during compute
            const size_t kbase = (size_t)(kt + 1) * 64 * HD;
            const int    vbase = (kt + 1) * 64;
            gl_lds16(kp + kbase + koff0, &Ks[buf ^ 1][c0 * 8]);
            gl_lds16(kp + kbase + koff1, &Ks[buf ^ 1][c1 * 8]);
            gl_lds16(vp + vbase + voff0, &Vs[buf ^ 1][c0 * 8]);
            gl_lds16(vp + vbase + voff1, &Vs[buf ^ 1][c1 * 8]);
        }
        const bool actA = (kt <= qtA);   // wave-uniform

        // S^T: A = K-frag (m = key), B = Q-frag (n = q); K-frag shared by A/B
        floatx4 sA[4], sB[4];
        #pragma unroll
        for (int j = 0; j < 4; j++) {
            sA[j] = (floatx4){0.f, 0.f, 0.f, 0.f};
            sB[j] = (floatx4){0.f, 0.f, 0.f, 0.f};
        }
        #pragma unroll
        for (int kb = 0; kb < 2; kb++)
            #pragma unroll
            for (int j = 0; j < 4; j++) {
                short8 kf = *(const short8*)(&Ks[buf][(j * 16 + l16) * 64 + (((kb * 4 + quad) ^ xsw) * 8)]);
                sB[j] = __builtin_amdgcn_mfma_f32_16x16x32_bf16(kf, qfB[kb], sB[j], 0, 0, 0);
                if (actA)
                    sA[j] = __builtin_amdgcn_mfma_f32_16x16x32_bf16(kf, qfA[kb], sA[j], 0, 0, 0);
            }

        if (kt == KT) {    // diagonal tile for B
            #pragma unroll
            for (int j = 0; j < 4; j++)
                #pragma unroll
                for (int r = 0; r < 4; r++) {
                    int key = kt * 64 + j * 16 + quad * 4 + r;
                    if (key > qB0 + l16) sB[j][r] = -1e30f;
                }
        }
        if (kt == qtA) {   // diagonal tile for A
            #pragma unroll
            for (int j = 0; j < 4; j++)
                #pragma unroll
                for (int r = 0; r < 4; r++) {
                    int key = kt * 64 + j * 16 + quad * 4 + r;
                    if (key > qA0 + l16) sA[j][r] = -1e30f;
                }
        }

        bf16x4 pfA[4], pfB[4];
        softmax_step(sB, mB, lB, oB, pfB);
        if (actA) softmax_step(sA, mA, lA, oA, pfA);

        // O^T += V^T · P^T  (A = V^T frag shared by A/B, B = P^T in regs)
        #pragma unroll
        for (int j = 0; j < 4; j++) {
            const int gchunk = 2 * j + (quad >> 1);
            #pragma unroll
            for (int db = 0; db < 4; db++) {
                bf16x4 vf = *(const bf16x4*)(&Vs[buf][(db * 16 + l16) * 64 +
                                                      ((gchunk ^ xsw) * 8) + (quad & 1) * 4]);
                oB[db] = MFMA16(vf, pfB[j], oB[db]);
                if (actA) oA[db] = MFMA16(vf, pfA[j], oA[db]);
            }
        }
    }

    const float invA = 1.0f / lA, invB = 1.0f / lB;
    const int tA = qA0 + l16, tB = qB0 + l16;
    #pragma unroll
    for (int db = 0; db < 4; db++) {
        union { ushort4 w; unsigned u[2]; } ou;
        ou.u[0] = pkbf(oA[db][0] * invA, oA[db][1] * invA);
        ou.u[1] = pkbf(oA[db][2] * invA, oA[db][3] * invA);
        *(ushort4*)(Oout + (((size_t)b * T_SEQ + tA) * NH + h) * HD + db * 16 + quad * 4) = ou.w;
        ou.u[0] = pkbf(oB[db][0] * invB, oB[db][1] * invB);
        ou.u[1] = pkbf(oB[db][2] * invB, oB[db][3] * invB);
        *(ushort4*)(Oout + (((size_t)b * T_SEQ + tB) * NH + h) * HD + db * 16 + quad * 4) = ou.w;
    }
}

extern "C" void kernel_launch(void* const* d_in, const int* in_sizes, int n_in,
                              void* d_out, int out_size, void* d_ws, size_t ws_size,
                              hipStream_t stream) {
    const float* x    = (const float*)d_in[0];   // [2,2048,1024] fp32
    const float* Wqkv = (const float*)d_in[1];   // [1024,3072]  fp32
    const float* Wout = (const float*)d_in[2];   // [1024,1024]  fp32
    ushort* ws = (ushort*)d_ws;

    ushort* wt_qkv = ws;                               // bf16 [3072][1024]
    ushort* wt_out = wt_qkv + 3072 * 1024;             // bf16 [1024][1024]
    ushort* q_ws   = wt_out + 1024 * 1024;             // bf16 [B,H,T,hd] (pre-scaled)
    ushort* k_ws   = q_ws + 4194304;
    ushort* v_t    = k_ws + 4194304;                   // bf16 [B,H,hd,T]
    ushort* a_out  = v_t + 4194304;                    // bf16 [B,T,C]
    ushort* x_bf   = a_out + 4194304;                  // bf16 [B,T,C]

    transpose_f32_bf16<<<dim3(96, 32), 256, 0, stream>>>(Wqkv, wt_qkv, 1024, 3072);
    transpose_f32_bf16<<<dim3(32, 32), 256, 0, stream>>>(Wout, wt_out, 1024, 1024);
    convert_f32_bf16<<<dim3(2048), 256, 0, stream>>>(x, x_bf);

    gemm_bt<0><<<dim3(32, 24), 256, 0, stream>>>(x_bf, wt_qkv, q_ws, k_ws, v_t, 4096, 3072, 1024);

    attn_kernel<<<dim3(512), 256, 0, stream>>>(q_ws, k_ws, v_t, a_out);

    gemm_bt<1><<<dim3(32, 8), 256, 0, stream>>>(a_out, wt_out, (float*)d_out, nullptr, nullptr,
                                                4096, 1024, 1024);
}

// Round 9
// 187.761 us; speedup vs baseline: 1.3742x; 1.1797x over previous
//
#include <hip/hip_runtime.h>
#include <hip/hip_bf16.h>

typedef __attribute__((ext_vector_type(8))) short short8;
typedef __attribute__((ext_vector_type(4))) short bf16x4;
typedef __attribute__((ext_vector_type(4))) float floatx4;

#define T_SEQ 2048
#define NH    16
#define HD    64
#define QSCALE 0.18033688f   // 0.125 * log2(e): folded into Q at GEMM1 epilogue

// v_mfma_f32_16x16x16_bf16 (4 bf16/lane A,B; 4 f32/lane C)
#define MFMA16(a, b, c) __builtin_amdgcn_mfma_f32_16x16x16bf16_1k(a, b, c, 0, 0, 0)

__device__ __forceinline__ ushort f2bf(float f) {
    union { float f; unsigned u; } un; un.f = f;
    unsigned r = un.u + 0x7fff + ((un.u >> 16) & 1);
    return (ushort)(r >> 16);
}
__device__ __forceinline__ unsigned pkbf(float a, float b) {   // packed cvt (1 inst)
    __hip_bfloat162 t = __float22bfloat162_rn(float2{a, b});
    return *reinterpret_cast<unsigned*>(&t);
}

typedef const __attribute__((address_space(1))) unsigned int* gp1_t;
typedef __attribute__((address_space(3))) unsigned int* lp3_t;
__device__ __forceinline__ void gl_lds16(const ushort* g, ushort* l) {
    __builtin_amdgcn_global_load_lds((gp1_t)g, (lp3_t)l, 16, 0, 0);
}

// -------- fused prep: W transposes (fp32->bf16) + x convert ----------------
// blocks [0,3072): Wqkv transpose 1024x3072 -> bf16 [3072][1024]
// blocks [3072,4096): Wout transpose 1024x1024 -> bf16 [1024][1024]
// blocks [4096,6144): x fp32 -> bf16 elementwise
__global__ void prep_kernel(const float* __restrict__ Wqkv, const float* __restrict__ Wout,
                            const float* __restrict__ x, ushort* __restrict__ wt_qkv,
                            ushort* __restrict__ wt_out, ushort* __restrict__ x_bf) {
    __shared__ ushort tile[32][33];
    const int bid = blockIdx.x;
    if (bid >= 4096) {   // convert path
        size_t i = ((size_t)(bid - 4096) * 256 + threadIdx.x) * 8;
        float4 f0 = *(const float4*)(x + i);
        float4 f1 = *(const float4*)(x + i + 4);
        short8 v;
        v[0] = (short)f2bf(f0.x); v[1] = (short)f2bf(f0.y);
        v[2] = (short)f2bf(f0.z); v[3] = (short)f2bf(f0.w);
        v[4] = (short)f2bf(f1.x); v[5] = (short)f2bf(f1.y);
        v[6] = (short)f2bf(f1.z); v[7] = (short)f2bf(f1.w);
        *(short8*)(x_bf + i) = v;
        return;
    }
    const float* in; ushort* out; int R, C, gx, gy;
    if (bid < 3072) { in = Wqkv; out = wt_qkv; R = 1024; C = 3072; gx = bid % 96; gy = bid / 96; }
    else            { int t = bid - 3072; in = Wout; out = wt_out; R = 1024; C = 1024; gx = t & 31; gy = t >> 5; }
    const int tx = threadIdx.x & 31, ty = threadIdx.x >> 5;
    const int bx = gx * 32, by = gy * 32;
    #pragma unroll
    for (int i = ty; i < 32; i += 8)
        tile[i][tx] = f2bf(in[(size_t)(by + i) * C + bx + tx]);
    __syncthreads();
    #pragma unroll
    for (int i = ty; i < 32; i += 8)
        out[(size_t)(bx + i) * R + by + tx] = tile[tx][i];
}

// ---------------- GEMM: C[M][N] = A[M][K] * Bt[N][K]^T  (bf16 MFMA, fp32 acc) --
// EPI==0: scatter bf16 into q(pre-scaled)[B,H,T,hd], k[B,H,T,hd], vT[B,H,hd,T];
//         pure-V blocks (n0>=2048) store via LDS transpose (coalesced 16B).
// EPI==1: fp32 row-major [M][N]
template <int EPI>
__global__ __launch_bounds__(256, 2)
void gemm_bt(const ushort* __restrict__ A, const ushort* __restrict__ Bt,
             void* __restrict__ O0, ushort* __restrict__ O1, ushort* __restrict__ O2,
             int M, int N, int K) {
    __shared__ __align__(16) ushort smem[8704];   // As[4096] | Bs[4096]; reused 64x136 for V transpose
    ushort* As = smem;
    ushort* Bs = smem + 4096;
    const int tid  = threadIdx.x;
    const int wave = tid >> 6, lane = tid & 63;
    const int quad = lane >> 4, l16 = lane & 15;
    const int wm = (wave >> 1) * 64, wn = (wave & 1) * 64;
    const int m0 = blockIdx.x * 128, n0 = blockIdx.y * 128;

    const int c0 = tid, c1 = tid + 256;
    const int row0 = c0 >> 2, row1 = c1 >> 2;
    const int g0 = (((c0 & 3) ^ ((row0 >> 1) & 3))) * 8;
    const int g1 = (((c1 & 3) ^ ((row1 >> 1) & 3))) * 8;
    const ushort* aP0 = A  + (size_t)(m0 + row0) * K + g0;
    const ushort* aP1 = A  + (size_t)(m0 + row1) * K + g1;
    const ushort* bP0 = Bt + (size_t)(n0 + row0) * K + g0;
    const ushort* bP1 = Bt + (size_t)(n0 + row1) * K + g1;

    floatx4 acc[4][4];
    #pragma unroll
    for (int i = 0; i < 4; i++)
        #pragma unroll
        for (int j = 0; j < 4; j++)
            acc[i][j] = (floatx4){0.f, 0.f, 0.f, 0.f};

    const int col_sw = (quad ^ ((l16 >> 1) & 3)) * 8;

    for (int k0 = 0; k0 < K; k0 += 32) {
        __syncthreads();
        gl_lds16(aP0 + k0, &As[c0 * 8]);
        gl_lds16(aP1 + k0, &As[c1 * 8]);
        gl_lds16(bP0 + k0, &Bs[c0 * 8]);
        gl_lds16(bP1 + k0, &Bs[c1 * 8]);
        __syncthreads();
        short8 af[4], bf[4];
        #pragma unroll
        for (int i = 0; i < 4; i++)
            af[i] = *(const short8*)(&As[(wm + i * 16 + l16) * 32 + col_sw]);
        #pragma unroll
        for (int j = 0; j < 4; j++)
            bf[j] = *(const short8*)(&Bs[(wn + j * 16 + l16) * 32 + col_sw]);
        #pragma unroll
        for (int i = 0; i < 4; i++)
            #pragma unroll
            for (int j = 0; j < 4; j++)
                acc[i][j] = __builtin_amdgcn_mfma_f32_16x16x32_bf16(af[i], bf[j], acc[i][j], 0, 0, 0);
    }

    if (EPI == 0 && n0 >= 2048) {
        // pure V block: LDS transpose -> coalesced 16B stores into vT[B,H,hd,T]
        const int b = m0 >> 11;
        const int t0 = m0 & 2047;             // token base within batch (FIX: was m0)
        const int head0 = (n0 - 2048) >> 6;
        __syncthreads();                      // all waves done reading As/Bs
        #pragma unroll
        for (int nh = 0; nh < 2; nh++) {
            if ((wave & 1) == nh) {           // waves owning this 64-col half
                #pragma unroll
                for (int j = 0; j < 4; j++)
                    #pragma unroll
                    for (int i = 0; i < 4; i++) {
                        int nl = j * 16 + l16;
                        int mB = wm + i * 16 + quad * 4;
                        *(unsigned*)(&smem[nl * 136 + mB])     = pkbf(acc[i][j][0], acc[i][j][1]);
                        *(unsigned*)(&smem[nl * 136 + mB + 2]) = pkbf(acc[i][j][2], acc[i][j][3]);
                    }
            }
            __syncthreads();
            #pragma unroll
            for (int cc = 0; cc < 4; cc++) {
                int c = cc * 256 + tid;       // 1024 chunks of 8 ushorts
                int row = c >> 4, mcol = (c & 15) * 8;
                uint4 v = *(const uint4*)(&smem[row * 136 + mcol]);
                *(uint4*)(&O2[((size_t)(b * NH + head0 + nh) * HD + row) * T_SEQ + t0 + mcol]) = v;
            }
            __syncthreads();
        }
        return;
    }

    #pragma unroll
    for (int i = 0; i < 4; i++) {
        #pragma unroll
        for (int j = 0; j < 4; j++) {
            #pragma unroll
            for (int r = 0; r < 4; r++) {
                int m = m0 + wm + i * 16 + quad * 4 + r;
                int n = n0 + wn + j * 16 + l16;
                if (EPI == 0) {
                    int b = m >> 11, t = m & 2047;
                    int part = n >> 10, c = n & 1023;
                    int head = c >> 6, off = c & 63;
                    float av = acc[i][j][r];
                    if (part == 0) av *= QSCALE;     // pre-scale Q for attention
                    ushort v = f2bf(av);
                    if (part == 0) ((ushort*)O0)[(((size_t)(b * NH + head)) * T_SEQ + t) * HD + off] = v;
                    else           O1[(((size_t)(b * NH + head)) * T_SEQ + t) * HD + off] = v;
                } else {
                    ((float*)O0)[(size_t)m * N + n] = acc[i][j][r];
                }
            }
        }
    }
}

// -------- online-softmax step over one 64-key S^T tile (per-lane scalar state) --
__device__ __forceinline__ void softmax_step(floatx4 s[4], float& mst, float& lst,
                                             floatx4 o[4], bf16x4 pf[4]) {
    float t0 = fmaxf(fmaxf(s[0][0], s[0][1]), fmaxf(s[0][2], s[0][3]));
    float t1 = fmaxf(fmaxf(s[1][0], s[1][1]), fmaxf(s[1][2], s[1][3]));
    float t2 = fmaxf(fmaxf(s[2][0], s[2][1]), fmaxf(s[2][2], s[2][3]));
    float t3 = fmaxf(fmaxf(s[3][0], s[3][1]), fmaxf(s[3][2], s[3][3]));
    float t = fmaxf(fmaxf(t0, t1), fmaxf(t2, t3));
    t = fmaxf(t, __shfl_xor(t, 16));
    t = fmaxf(t, __shfl_xor(t, 32));
    float mnew  = fmaxf(mst, t);
    float alpha = exp2f(mst - mnew);
    mst = mnew;
    float lsum = 0.f;
    #pragma unroll
    for (int j = 0; j < 4; j++) {
        float p0 = exp2f(s[j][0] - mnew);
        float p1 = exp2f(s[j][1] - mnew);
        float p2 = exp2f(s[j][2] - mnew);
        float p3 = exp2f(s[j][3] - mnew);
        lsum += (p0 + p1) + (p2 + p3);
        union { bf16x4 v; unsigned u[2]; } pu;
        pu.u[0] = pkbf(p0, p1);
        pu.u[1] = pkbf(p2, p3);
        pf[j] = pu.v;
    }
    lsum += __shfl_xor(lsum, 16);
    lsum += __shfl_xor(lsum, 32);
    lst = lst * alpha + lsum;
    #pragma unroll
    for (int db = 0; db < 4; db++)
        #pragma unroll
        for (int r = 0; r < 4; r++) o[db][r] *= alpha;
}

// ---------------- flash attention, S^T formulation, balanced single q-tiles --
// Block = (bh, qt): 64 q rows, 4 waves x 16 rows. Grid 1024 = 4 blocks/CU.
// Co-resident sets {c,c+256,c+512,c+768} -> j in {r,r+8,r+16,r+24}; qt = f(j)
// chosen so per-CU iteration counts {r+1,16-r,17+r,32-r} sum to 66 (uniform),
// same bh per CU (K/V L2 locality). LDS fragment addresses hoisted; loop
// unrolled x2 so the double-buffer index is compile-time (imm ds offsets).
__global__ __launch_bounds__(256, 4)
void attn_kernel(const ushort* __restrict__ Q, const ushort* __restrict__ Kk,
                 const ushort* __restrict__ Vt, ushort* __restrict__ Oout) {
    __shared__ __align__(16) ushort Ks[2][64 * 64];
    __shared__ __align__(16) ushort Vs[2][64 * 64];
    const int tid  = threadIdx.x;
    const int wave = tid >> 6, lane = tid & 63;
    const int quad = lane >> 4, l16 = lane & 15;
    const int idx = blockIdx.x;
    const int bh = idx & 31;
    const int j = idx >> 5;                 // 0..31
    const int oct = j >> 3, r = j & 7;
    const int qt = (oct == 0) ? r : (oct == 1) ? (15 - r) : (oct == 2) ? (16 + r) : (31 - r);
    const int b = bh >> 4, h = bh & 15;

    const ushort* qp = Q  + (size_t)bh * T_SEQ * HD;
    const ushort* kp = Kk + (size_t)bh * T_SEQ * HD;
    const ushort* vp = Vt + (size_t)bh * HD * T_SEQ;

    const int q0w = qt * 64 + wave * 16;    // this wave's 16 q rows

    short8 qf[2];                           // B-operand: n=q=l16, k=d
    #pragma unroll
    for (int kb = 0; kb < 2; kb++)
        qf[kb] = *(const short8*)(qp + (size_t)(q0w + l16) * HD + kb * 32 + quad * 8);

    floatx4 o[4];                           // O^T accum: d = db*16+quad*4+r, q = l16
    #pragma unroll
    for (int db = 0; db < 4; db++) o[db] = (floatx4){0.f, 0.f, 0.f, 0.f};
    float mst = -1e30f, lst = 0.f;

    // staging: 512 chunks of 16B per operand; thread covers c = tid, tid+256.
    const int c0 = tid, c1 = tid + 256;
    const int r0 = c0 >> 3, r1 = c1 >> 3;
    const int g0 = ((c0 & 7) ^ (r0 & 7)) * 8;
    const int g1 = ((c1 & 7) ^ (r1 & 7)) * 8;
    const size_t koff0 = (size_t)r0 * HD + g0,     koff1 = (size_t)r1 * HD + g1;
    const size_t voff0 = (size_t)r0 * T_SEQ + g0,  voff1 = (size_t)r1 * T_SEQ + g1;

    gl_lds16(kp + koff0, &Ks[0][c0 * 8]);
    gl_lds16(kp + koff1, &Ks[0][c1 * 8]);
    gl_lds16(vp + voff0, &Vs[0][c0 * 8]);
    gl_lds16(vp + voff1, &Vs[0][c1 * 8]);

    // hoisted LDS fragment addresses (ushort indices); j*1024/db*1024 become imm
    const int xsw = (l16 & 7), qh = quad >> 1, ql = quad & 1;
    const int ka0 = l16 * 64 + ((quad ^ xsw) * 8);
    const int ka1 = l16 * 64 + (((4 + quad) ^ xsw) * 8);
    int va[4];
    #pragma unroll
    for (int jj = 0; jj < 4; jj++)
        va[jj] = l16 * 64 + (((2 * jj + qh) ^ xsw) * 8) + ql * 4;

#define ATT_STEP(BUF, KT)                                                        \
    {                                                                            \
        __syncthreads();                                                         \
        if ((KT) < qt) {                                                         \
            const size_t kbase = (size_t)((KT) + 1) * 64 * HD;                   \
            const int    vbase = ((KT) + 1) * 64;                                \
            gl_lds16(kp + kbase + koff0, &Ks[(BUF) ^ 1][c0 * 8]);                \
            gl_lds16(kp + kbase + koff1, &Ks[(BUF) ^ 1][c1 * 8]);                \
            gl_lds16(vp + vbase + voff0, &Vs[(BUF) ^ 1][c0 * 8]);                \
            gl_lds16(vp + vbase + voff1, &Vs[(BUF) ^ 1][c1 * 8]);                \
        }                                                                        \
        floatx4 s[4];                                                            \
        _Pragma("unroll")                                                        \
        for (int jj = 0; jj < 4; jj++) s[jj] = (floatx4){0.f, 0.f, 0.f, 0.f};    \
        _Pragma("unroll")                                                        \
        for (int jj = 0; jj < 4; jj++) {                                         \
            short8 kf0 = *(const short8*)(&Ks[BUF][ka0 + jj * 1024]);            \
            s[jj] = __builtin_amdgcn_mfma_f32_16x16x32_bf16(kf0, qf[0], s[jj], 0, 0, 0); \
        }                                                                        \
        _Pragma("unroll")                                                        \
        for (int jj = 0; jj < 4; jj++) {                                         \
            short8 kf1 = *(const short8*)(&Ks[BUF][ka1 + jj * 1024]);            \
            s[jj] = __builtin_amdgcn_mfma_f32_16x16x32_bf16(kf1, qf[1], s[jj], 0, 0, 0); \
        }                                                                        \
        if ((KT) == qt) {                                                        \
            _Pragma("unroll")                                                    \
            for (int jj = 0; jj < 4; jj++)                                       \
                _Pragma("unroll")                                                \
                for (int rr = 0; rr < 4; rr++) {                                 \
                    int key = (KT) * 64 + jj * 16 + quad * 4 + rr;               \
                    if (key > q0w + l16) s[jj][rr] = -1e30f;                     \
                }                                                                \
        }                                                                        \
        bf16x4 pf[4];                                                            \
        softmax_step(s, mst, lst, o, pf);                                        \
        _Pragma("unroll")                                                        \
        for (int jj = 0; jj < 4; jj++)                                           \
            _Pragma("unroll")                                                    \
            for (int db = 0; db < 4; db++) {                                     \
                bf16x4 vf = *(const bf16x4*)(&Vs[BUF][va[jj] + db * 1024]);      \
                o[db] = MFMA16(vf, pf[jj], o[db]);                               \
            }                                                                    \
    }

    int kt = 0;
    for (; kt + 1 <= qt; kt += 2) {
        ATT_STEP(0, kt)
        ATT_STEP(1, kt + 1)
    }
    if (kt <= qt) ATT_STEP(0, kt)
#undef ATT_STEP

    const float inv = 1.0f / lst;
    const int t = q0w + l16;
    #pragma unroll
    for (int db = 0; db < 4; db++) {
        union { ushort4 w; unsigned u[2]; } ou;
        ou.u[0] = pkbf(o[db][0] * inv, o[db][1] * inv);
        ou.u[1] = pkbf(o[db][2] * inv, o[db][3] * inv);
        *(ushort4*)(Oout + (((size_t)b * T_SEQ + t) * NH + h) * HD + db * 16 + quad * 4) = ou.w;
    }
}

extern "C" void kernel_launch(void* const* d_in, const int* in_sizes, int n_in,
                              void* d_out, int out_size, void* d_ws, size_t ws_size,
                              hipStream_t stream) {
    const float* x    = (const float*)d_in[0];   // [2,2048,1024] fp32
    const float* Wqkv = (const float*)d_in[1];   // [1024,3072]  fp32
    const float* Wout = (const float*)d_in[2];   // [1024,1024]  fp32
    ushort* ws = (ushort*)d_ws;

    ushort* wt_qkv = ws;                               // bf16 [3072][1024]
    ushort* wt_out = wt_qkv + 3072 * 1024;             // bf16 [1024][1024]
    ushort* q_ws   = wt_out + 1024 * 1024;             // bf16 [B,H,T,hd] (pre-scaled)
    ushort* k_ws   = q_ws + 4194304;
    ushort* v_t    = k_ws + 4194304;                   // bf16 [B,H,hd,T]
    ushort* a_out  = v_t + 4194304;                    // bf16 [B,T,C]
    ushort* x_bf   = a_out + 4194304;                  // bf16 [B,T,C]

    prep_kernel<<<dim3(6144), 256, 0, stream>>>(Wqkv, Wout, x, wt_qkv, wt_out, x_bf);

    gemm_bt<0><<<dim3(32, 24), 256, 0, stream>>>(x_bf, wt_qkv, q_ws, k_ws, v_t, 4096, 3072, 1024);

    attn_kernel<<<dim3(1024), 256, 0, stream>>>(q_ws, k_ws, v_t, a_out);

    gemm_bt<1><<<dim3(32, 8), 256, 0, stream>>>(a_out, wt_out, (float*)d_out, nullptr, nullptr,
                                                4096, 1024, 1024);
}